// Round 1
// baseline (113.621 us; speedup 1.0000x reference)
//
#include <hip/hip_runtime.h>
#include <hip/hip_bf16.h>
#include <stdint.h>

// Problem constants
#define B_ROWS 8192
#define HDIM   1024
#define IDIM   128
#define KDIM   1152   // I + H
#define TMAX   128

typedef unsigned short u16;
typedef __bf16 bf16x8 __attribute__((ext_vector_type(8)));
typedef float  f32x4  __attribute__((ext_vector_type(4)));

static __device__ __forceinline__ u16 f2bf(float f) {
  union { float f; unsigned u; } v; v.f = f;
  unsigned r = v.u + 0x7FFFu + ((v.u >> 16) & 1u);   // round-to-nearest-even
  return (u16)(r >> 16);
}
static __device__ __forceinline__ float bf2f(u16 b) {
  union { unsigned u; float f; } v; v.u = ((unsigned)b) << 16; return v.f;
}

// ---------------------------------------------------------------------------
// Kernel 1: convert everything to bf16 staging buffers.
//   region 0: [W_r|W_z|W_h] -> WB  (3*1024*1152 elems)
//   region 1: h -> A1 cols 128..1151
//   region 2: x = x_coeffs[clip(int(t))] -> A1 cols 0..127 AND A2 cols 0..127
// ---------------------------------------------------------------------------
#define W_CHUNKS  (3*1024*1152/4)       // 884736
#define H_CHUNKS  (B_ROWS*HDIM/4)       // 2097152
#define X_CHUNKS  (B_ROWS*IDIM/4)       // 262144
#define W_BLOCKS  (W_CHUNKS/256)        // 3456
#define H_BLOCKS  (H_CHUNKS/256)        // 8192
#define X_BLOCKS  (X_CHUNKS/256)        // 1024
#define CV_BLOCKS (W_BLOCKS + H_BLOCKS + X_BLOCKS)

__global__ __launch_bounds__(256)
void convert_kernel(const float* __restrict__ t,
                    const float* __restrict__ h,
                    const float* __restrict__ xc,
                    const float* __restrict__ Wr,
                    const float* __restrict__ Wz,
                    const float* __restrict__ Wh,
                    u16* __restrict__ WB,
                    u16* __restrict__ A1,
                    u16* __restrict__ A2)
{
  const int b = blockIdx.x;
  const int tid = threadIdx.x;
  if (b < W_BLOCKS) {
    const int g = b * 256 + tid;
    const int e = g * 4;
    const int S = 1024 * KDIM;          // 1179648, divisible by 4
    float4 v;
    if (e < S)            v = *reinterpret_cast<const float4*>(Wr + e);
    else if (e < 2 * S)   v = *reinterpret_cast<const float4*>(Wz + (e - S));
    else                  v = *reinterpret_cast<const float4*>(Wh + (e - 2 * S));
    ushort4 o; o.x = f2bf(v.x); o.y = f2bf(v.y); o.z = f2bf(v.z); o.w = f2bf(v.w);
    *reinterpret_cast<ushort4*>(WB + e) = o;
  } else if (b < W_BLOCKS + H_BLOCKS) {
    const int g = (b - W_BLOCKS) * 256 + tid;
    const int e = g * 4;                // flat into h [8192][1024]
    const int row = e >> 10, col = e & 1023;
    float4 v = *reinterpret_cast<const float4*>(h + e);
    ushort4 o; o.x = f2bf(v.x); o.y = f2bf(v.y); o.z = f2bf(v.z); o.w = f2bf(v.w);
    *reinterpret_cast<ushort4*>(A1 + (size_t)row * KDIM + IDIM + col) = o;
  } else {
    const int g = (b - W_BLOCKS - H_BLOCKS) * 256 + tid;
    const int e = g * 4;                // flat into x [8192][128]
    int ti = (int)t[0];                 // trunc toward zero, matches astype(int32)
    ti = ti < 0 ? 0 : (ti > TMAX - 1 ? TMAX - 1 : ti);
    const int row = e >> 7, col = e & 127;
    float4 v = *reinterpret_cast<const float4*>(xc + (size_t)ti * B_ROWS * IDIM + e);
    ushort4 o; o.x = f2bf(v.x); o.y = f2bf(v.y); o.z = f2bf(v.z); o.w = f2bf(v.w);
    *reinterpret_cast<ushort4*>(A1 + (size_t)row * KDIM + col) = o;
    *reinterpret_cast<ushort4*>(A2 + (size_t)row * KDIM + col) = o;
  }
}

// ---------------------------------------------------------------------------
// GEMM: C[m][n] = sum_k A[m][k] * W[n][k]   (A, W bf16 row-major, K = 1152)
// 128x128 tile, BK=64, 4 waves (2x2), mfma_f32_16x16x32_bf16, 4x4 frags/wave.
// global_load_lds width-16 with both-sides XOR chunk swizzle (bank-conflict-free).
// MODE 0 (N=2048): n<1024 -> r=sigmoid, store bf16(r*h) into A2 col 128+n
//                  n>=1024 -> z=sigmoid, store bf16(1-z) into omz
// MODE 1 (N=1024): htilde=tanh, out = (1-z)*(htilde - h)  (fp32)
// ---------------------------------------------------------------------------
template<int MODE, int N>
__global__ __launch_bounds__(256, 2)
void gemm_fused(const u16* __restrict__ A,
                const u16* __restrict__ W,
                const float* __restrict__ hf,
                u16* __restrict__ A2,
                u16* __restrict__ omz,
                float* __restrict__ out)
{
  __shared__ u16 As[128 * 64];
  __shared__ u16 Bs[128 * 64];

  const int tid  = threadIdx.x;
  const int lane = tid & 63;
  const int wave = tid >> 6;
  const int wm = wave >> 1, wn = wave & 1;
  const int NB = N / 128;
  const int bn = blockIdx.x % NB;
  const int bm = blockIdx.x / NB;
  const int rowBase = bm * 128;
  const int colBase = bn * 128;

  const int lr  = lane & 15;   // A-row / B-col within fragment
  const int lkq = lane >> 4;   // k quadrant (0..3), 8 elems each

  f32x4 acc[4][4];
  f32x4 zero = {0.f, 0.f, 0.f, 0.f};
  #pragma unroll
  for (int i = 0; i < 4; ++i)
    #pragma unroll
    for (int j = 0; j < 4; ++j) acc[i][j] = zero;

  for (int kt = 0; kt < KDIM / 64; ++kt) {
    const int kBase = kt * 64;
    // ---- stage 128x64 A-tile and B-tile: 1024 16B-chunks each, 4 iters ----
    #pragma unroll
    for (int it = 0; it < 4; ++it) {
      const int c    = it * 256 + tid;       // chunk index
      const int row  = c >> 3;               // 8 chunks (128B) per row
      const int col8 = (c & 7) ^ (row & 7);  // pre-swizzled global source
      const u16* ga = A + (size_t)(rowBase + row) * KDIM + kBase + col8 * 8;
      __builtin_amdgcn_global_load_lds(
          (const __attribute__((address_space(1))) void*)ga,
          (__attribute__((address_space(3))) void*)(As + c * 8), 16, 0, 0);
      const u16* gb = W + (size_t)(colBase + row) * KDIM + kBase + col8 * 8;
      __builtin_amdgcn_global_load_lds(
          (const __attribute__((address_space(1))) void*)gb,
          (__attribute__((address_space(3))) void*)(Bs + c * 8), 16, 0, 0);
    }
    __syncthreads();   // drains vmcnt before barrier -> tiles ready

    // ---- compute: 2 k-substeps x 4x4 MFMA ----
    #pragma unroll
    for (int kk = 0; kk < 2; ++kk) {
      bf16x8 af[4], bfr[4];
      #pragma unroll
      for (int mf = 0; mf < 4; ++mf) {
        const int row = wm * 64 + mf * 16 + lr;
        const int cc  = (kk * 4 + lkq) ^ (row & 7);   // swizzled read
        af[mf] = *reinterpret_cast<const bf16x8*>(&As[row * 64 + cc * 8]);
      }
      #pragma unroll
      for (int nf = 0; nf < 4; ++nf) {
        const int row = wn * 64 + nf * 16 + lr;
        const int cc  = (kk * 4 + lkq) ^ (row & 7);
        bfr[nf] = *reinterpret_cast<const bf16x8*>(&Bs[row * 64 + cc * 8]);
      }
      #pragma unroll
      for (int mf = 0; mf < 4; ++mf)
        #pragma unroll
        for (int nf = 0; nf < 4; ++nf)
          acc[mf][nf] = __builtin_amdgcn_mfma_f32_16x16x32_bf16(
              af[mf], bfr[nf], acc[mf][nf], 0, 0, 0);
    }
    __syncthreads();   // protect LDS before next stage
  }

  // ---- epilogue: C/D layout col = lane&15, row = (lane>>4)*4 + r ----
  #pragma unroll
  for (int mf = 0; mf < 4; ++mf) {
    #pragma unroll
    for (int nf = 0; nf < 4; ++nf) {
      f32x4 v = acc[mf][nf];
      const int col = colBase + wn * 64 + nf * 16 + lr;
      #pragma unroll
      for (int r = 0; r < 4; ++r) {
        const int row = rowBase + wm * 64 + mf * 16 + lkq * 4 + r;
        const float x = v[r];
        if (MODE == 0) {
          const float s = 1.f / (1.f + __expf(-x));   // sigmoid
          if (col < HDIM) {
            const float rh = s * hf[(size_t)row * HDIM + col];
            A2[(size_t)row * KDIM + IDIM + col] = f2bf(rh);
          } else {
            omz[(size_t)row * HDIM + (col - HDIM)] = f2bf(1.f - s);
          }
        } else {
          const float e  = __expf(2.f * x);
          const float ht = 1.f - 2.f / (e + 1.f);     // tanh
          const float o  = bf2f(omz[(size_t)row * HDIM + col]);
          out[(size_t)row * HDIM + col] = o * (ht - hf[(size_t)row * HDIM + col]);
        }
      }
    }
  }
}

// ---------------------------------------------------------------------------
extern "C" void kernel_launch(void* const* d_in, const int* in_sizes, int n_in,
                              void* d_out, int out_size, void* d_ws, size_t ws_size,
                              hipStream_t stream) {
  const float* t  = (const float*)d_in[0];
  const float* h  = (const float*)d_in[1];
  const float* xc = (const float*)d_in[2];
  const float* Wr = (const float*)d_in[3];
  const float* Wz = (const float*)d_in[4];
  const float* Wh = (const float*)d_in[5];
  float* out = (float*)d_out;

  // Workspace layout (bf16 elements):
  //   WB : [2048+1024][1152]  (W_r rows, W_z rows, then W_h rows)
  //   A1 : [8192][1152]  = [x | h]
  //   A2 : [8192][1152]  = [x | r*h]
  //   omz: [8192][1024]  = 1 - z
  u16* WB  = (u16*)d_ws;
  u16* A1  = WB + (size_t)3 * 1024 * KDIM;
  u16* A2  = A1 + (size_t)B_ROWS * KDIM;
  u16* omz = A2 + (size_t)B_ROWS * KDIM;
  // total: 7.08 + 18.87 + 18.87 + 16.78 MB = 61.6 MB of ws

  convert_kernel<<<CV_BLOCKS, 256, 0, stream>>>(t, h, xc, Wr, Wz, Wh, WB, A1, A2);

  // GEMM1: A1 x [W_r;W_z]^T -> r,z ; writes A2 (r*h) and omz (1-z)
  gemm_fused<0, 2048><<<(B_ROWS / 128) * (2048 / 128), 256, 0, stream>>>(
      A1, WB, h, A2, omz, out);

  // GEMM2: A2 x W_h^T -> htilde ; writes out = (1-z)*(htilde - h)
  gemm_fused<1, 1024><<<(B_ROWS / 128) * (1024 / 128), 256, 0, stream>>>(
      A2, WB + (size_t)2048 * KDIM, h, nullptr, omz, out);
}